// Round 7
// baseline (412.208 us; speedup 1.0000x reference)
//
#include <hip/hip_runtime.h>

namespace {
constexpr int IMG_W = 512, IMG_H = 512;
constexpr int TW = 32, TH = 32;
constexpr int IN_W = TW + 10, IN_H = TH + 10;   // 42
constexpr int S12_STR = 46;  // float2 units; phase-2 b128 reads bank-minimal
constexpr int CH_PER_BLOCK = 4;
constexpr float C1c = 0.01f * 0.01f;
constexpr float C2c = 0.03f * 0.03f;

constexpr float GW[11] = {
    1.0283799e-03f, 7.5987582e-03f, 3.6000773e-02f, 1.0936069e-01f,
    2.1300554e-01f, 2.6601172e-01f, 2.1300554e-01f, 1.0936069e-01f,
    3.6000773e-02f, 7.5987582e-03f, 1.0283799e-03f
};
constexpr float GWZ(int t) { return (t >= 0 && t < 11) ? GW[t] : 0.f; }

using v2f = __attribute__((ext_vector_type(2))) float;
using v4f = __attribute__((ext_vector_type(4))) float;

// In-place packed FMA, weight in SGPR pair: acc += w * a.
__device__ __forceinline__ void pkfma(v2f& acc, v2f w, v2f a) {
    asm("v_pk_fma_f32 %0, %1, %2, %0" : "+v"(acc) : "s"(w), "v"(a));
}
__device__ __forceinline__ v2f pkmul(v2f a, v2f b) {
    v2f d;
    asm("v_pk_mul_f32 %0, %1, %2" : "=v"(d) : "v"(a), "v"(b));
    return d;
}
__device__ __forceinline__ v2f bcast(float w) { v2f r; r.x = w; r.y = w; return r; }

// h-planes: stride 32 + rotate swizzle (col+row)&31
__device__ __forceinline__ int hidx(int row, int col) {
    return row * 32 + ((col + row) & 31);
}
}

__global__ __launch_bounds__(256, 6) void ssim_tile_kernel(
        const float* __restrict__ img1, const float* __restrict__ img2,
        double* __restrict__ acc)
{
    union SharedU {
        v2f s12[IN_H * S12_STR];                // 15456 B
        struct {
            v4f   h4 [IN_H * 32];               // 21504 B (mu1,mu2,Exx,Eyy) swizzled
            float hab[IN_H * 32];               //  5376 B (Exy) swizzled
        } h;
    };
    __shared__ SharedU u;
    __shared__ float wred[4];

    const int tid = threadIdx.x;
    const int x0 = blockIdx.x * TW - 5;
    const int y0 = blockIdx.y * TH - 5;
    const bool interior =
        blockIdx.x > 0 && blockIdx.x < gridDim.x - 1 &&
        blockIdx.y > 0 && blockIdx.y < gridDim.y - 1;

    // Phase-1 addressing: channel-independent parts computed once.
    const int r0 = tid / IN_W;
    const int c0 = tid - r0 * IN_W;
    const int goff0 = (y0 + r0) * IMG_W + (x0 + c0);
    const int loff0 = r0 * S12_STR + c0;

    const int r2 = tid >> 2;            // phase-2 row
    const int cb = (tid & 3) * 8;       // phase-2 col base
    const int c3 = tid & 31;            // phase-3 col
    const int rb = (tid >> 5) * 4;      // phase-3 row base

    float lsum = 0.f;

#pragma unroll 1
    for (int ch = 0; ch < CH_PER_BLOCK; ++ch) {
        const size_t base =
            (size_t)(blockIdx.z * CH_PER_BLOCK + ch) * (IMG_W * IMG_H);
        const float* p1 = img1 + base;
        const float* p2 = img2 + base;

        // ---- Phase 1: global -> LDS, incremental addressing ----
        {
            int r = r0, c = c0, goff = goff0, loff = loff0;
            if (interior) {
#pragma unroll
                for (int i = 0; i < 7; ++i) {
                    if (i < 6 || tid < IN_H * IN_W - 6 * 256) {   // 228
                        v2f t; t.x = p1[goff]; t.y = p2[goff];
                        u.s12[loff] = t;
                    }
                    const bool wrap = (c + 4) >= IN_W;
                    c    += wrap ? 4 - IN_W : 4;
                    goff += wrap ? 7 * IMG_W - (IN_W - 4) : 6 * IMG_W + 4;
                    loff += wrap ? 7 * S12_STR - (IN_W - 4) : 6 * S12_STR + 4;
                    r    += wrap ? 7 : 6;
                }
            } else {
#pragma unroll
                for (int i = 0; i < 7; ++i) {
                    if (i < 6 || tid < IN_H * IN_W - 6 * 256) {
                        const int gy = y0 + r, gx = x0 + c;
                        v2f t; t.x = 0.f; t.y = 0.f;
                        if (gy >= 0 && gy < IMG_H && gx >= 0 && gx < IMG_W) {
                            t.x = p1[goff]; t.y = p2[goff];
                        }
                        u.s12[loff] = t;
                    }
                    const bool wrap = (c + 4) >= IN_W;
                    c    += wrap ? 4 - IN_W : 4;
                    goff += wrap ? 7 * IMG_W - (IN_W - 4) : 6 * IMG_W + 4;
                    loff += wrap ? 7 * S12_STR - (IN_W - 4) : 6 * S12_STR + 4;
                    r    += wrap ? 7 : 6;
                }
            }
        }
        __syncthreads();

        // ---- Phase 2: horizontal 11-tap, scatter form, packed xy ----
        v2f mu8[8], sq8[8], xy2[4];
        if (tid < 168) {
#pragma unroll
            for (int j = 0; j < 8; ++j) { mu8[j] = bcast(0.f); sq8[j] = bcast(0.f); }
#pragma unroll
            for (int p = 0; p < 4; ++p) xy2[p] = bcast(0.f);
            const v4f* srow = (const v4f*)&u.s12[r2 * S12_STR + cb];
#pragma unroll
            for (int m = 0; m < 9; ++m) {
                const v4f q = srow[m];
#pragma unroll
                for (int half = 0; half < 2; ++half) {
                    const int k = 2 * m + half;
                    v2f v;
                    v.x = half ? q.z : q.x;
                    v.y = half ? q.w : q.y;
                    const v2f a2 = pkmul(v, v);
                    v2f xyd;                       // {x*y, x*y}
                    xyd.x = v.x * v.y;
                    xyd.y = xyd.x;
#pragma unroll
                    for (int j = 0; j < 8; ++j) {
                        const int t = k - j;
                        if (t >= 0 && t < 11) {
                            const v2f w2 = bcast(GW[t]);
                            pkfma(mu8[j], w2, v);
                            pkfma(sq8[j], w2, a2);
                        }
                    }
#pragma unroll
                    for (int p = 0; p < 4; ++p) {
                        const int t = k - 2 * p;
                        if (t >= 0 && t <= 11) {
                            v2f wp; wp.x = GWZ(t); wp.y = GWZ(t - 1);
                            pkfma(xy2[p], wp, xyd);
                        }
                    }
                }
            }
        }
        __syncthreads();            // all reads of s12 done; safe to overwrite
        if (tid < 168) {
#pragma unroll
            for (int j = 0; j < 8; ++j) {
                const int idx = hidx(r2, cb + j);
                v4f q;
                q.x = mu8[j].x; q.y = mu8[j].y;
                q.z = sq8[j].x; q.w = sq8[j].y;
                u.h.h4 [idx] = q;
                u.h.hab[idx] = (j & 1) ? xy2[j >> 1].y : xy2[j >> 1].x;
            }
        }
        __syncthreads();

        // ---- Phase 3: vertical 11-tap + SSIM, scatter form, 4 rows/thread ----
        v2f mu4[4], sg4[4];
        float xy4[4];
#pragma unroll
        for (int j = 0; j < 4; ++j) {
            mu4[j] = bcast(0.f); sg4[j] = bcast(0.f); xy4[j] = 0.f;
        }
#pragma unroll
        for (int k = 0; k < 14; ++k) {
            const int idx = hidx(rb + k, c3);
            const v4f q = u.h.h4[idx];
            const float hx = u.h.hab[idx];
            v2f hm; hm.x = q.x; hm.y = q.y;
            v2f hs; hs.x = q.z; hs.y = q.w;
#pragma unroll
            for (int j = 0; j < 4; ++j) {
                const int t = k - j;
                if (t >= 0 && t < 11) {
                    const v2f w2 = bcast(GW[t]);
                    pkfma(mu4[j], w2, hm);
                    pkfma(sg4[j], w2, hs);
                    xy4[j] = fmaf(GW[t], hx, xy4[j]);
                }
            }
        }
#pragma unroll
        for (int j = 0; j < 4; ++j) {
            const v2f musq = pkmul(mu4[j], mu4[j]);      // {mu1^2, mu2^2}
            const float mu12 = mu4[j].x * mu4[j].y;
            const float s1 = sg4[j].x - musq.x, s2 = sg4[j].y - musq.y;
            const float s12v = xy4[j] - mu12;
            const float num = (2.f * mu12 + C1c) * (2.f * s12v + C2c);
            const float den = (musq.x + musq.y + C1c) * (s1 + s2 + C2c);
            lsum += __fdividef(num, den);
        }
        __syncthreads();    // phase-3 h reads done before next tile's s12 write
    }

    // ---- Phase 4: block reduce (once) -> double atomic into 256 ws slots ----
#pragma unroll
    for (int off = 32; off > 0; off >>= 1)
        lsum += __shfl_down(lsum, off, 64);
    if ((tid & 63) == 0) wred[tid >> 6] = lsum;
    __syncthreads();
    if (tid == 0) {
        const int bid = (blockIdx.z * gridDim.y + blockIdx.y) * gridDim.x + blockIdx.x;
        unsafeAtomicAdd(&acc[bid & 255],
                        (double)(wred[0] + wred[1] + wred[2] + wred[3]));
    }
}

__global__ __launch_bounds__(256) void ssim_final_kernel(
        const double* __restrict__ acc, float* __restrict__ out, double inv_total)
{
    const int tid = threadIdx.x;
    double a = acc[tid];
#pragma unroll
    for (int off = 32; off > 0; off >>= 1)
        a += __shfl_down(a, off, 64);
    __shared__ double ws[4];
    if ((tid & 63) == 0) ws[tid >> 6] = a;
    __syncthreads();
    if (tid == 0)
        out[0] = (float)((ws[0] + ws[1] + ws[2] + ws[3]) * inv_total);
}

extern "C" void kernel_launch(void* const* d_in, const int* in_sizes, int n_in,
                              void* d_out, int out_size, void* d_ws, size_t ws_size,
                              hipStream_t stream)
{
    const float* img1 = (const float*)d_in[0];
    const float* img2 = (const float*)d_in[1];
    double* acc = (double*)d_ws;

    hipMemsetAsync(d_ws, 0, 256 * sizeof(double), stream);

    const int nch = in_sizes[0] / (IMG_W * IMG_H);      // 16*3 = 48
    dim3 grid(IMG_W / TW, IMG_H / TH, nch / CH_PER_BLOCK);  // 16 x 16 x 12
    ssim_tile_kernel<<<grid, 256, 0, stream>>>(img1, img2, acc);

    const double inv_total = 1.0 / (double)in_sizes[0];
    ssim_final_kernel<<<1, 256, 0, stream>>>(acc, (float*)d_out, inv_total);
}

// Round 8
// 271.877 us; speedup vs baseline: 1.5162x; 1.5162x over previous
//
#include <hip/hip_runtime.h>

namespace {
constexpr int IMG_W = 512, IMG_H = 512;
constexpr int TW = 32, TH = 32;
constexpr int IN_W = TW + 10, IN_H = TH + 10;   // 42
constexpr int S12_STR = 46;  // float2 units; phase-2 b128 reads bank-minimal
constexpr int CH_PER_BLOCK = 4;
constexpr float C1c = 0.01f * 0.01f;
constexpr float C2c = 0.03f * 0.03f;

constexpr float GW[11] = {
    1.0283799e-03f, 7.5987582e-03f, 3.6000773e-02f, 1.0936069e-01f,
    2.1300554e-01f, 2.6601172e-01f, 2.1300554e-01f, 1.0936069e-01f,
    3.6000773e-02f, 7.5987582e-03f, 1.0283799e-03f
};
constexpr float GWZ(int t) { return (t >= 0 && t < 11) ? GW[t] : 0.f; }

using v2f = __attribute__((ext_vector_type(2))) float;
using v4f = __attribute__((ext_vector_type(4))) float;

// In-place packed FMA, weight in SGPR pair: acc += w * a.
__device__ __forceinline__ void pkfma(v2f& acc, v2f w, v2f a) {
    asm("v_pk_fma_f32 %0, %1, %2, %0" : "+v"(acc) : "s"(w), "v"(a));
}
__device__ __forceinline__ v2f pkmul(v2f a, v2f b) {
    v2f d;
    asm("v_pk_mul_f32 %0, %1, %2" : "=v"(d) : "v"(a), "v"(b));
    return d;
}
__device__ __forceinline__ v2f bcast(float w) { v2f r; r.x = w; r.y = w; return r; }

// h-planes: stride 32 + rotate swizzle (col+row)&31
__device__ __forceinline__ int hidx(int row, int col) {
    return row * 32 + ((col + row) & 31);
}
}

// (256,4): VGPR cap 128 -- R7's spill came from the (256,6)=85-VGPR cap; the
// channel-loop live set (~95) must stay in registers. LDS (27136 B) still
// admits 6 blocks/CU; residency will be VGPR-bound ~5.
__global__ __launch_bounds__(256, 4) void ssim_tile_kernel(
        const float* __restrict__ img1, const float* __restrict__ img2,
        double* __restrict__ acc)
{
    union SharedU {
        v2f s12[IN_H * S12_STR];                // 15456 B
        struct {
            v4f   h4 [IN_H * 32];               // 21504 B (mu1,mu2,Exx,Eyy) swizzled
            float hab[IN_H * 32];               //  5376 B (Exy) swizzled
        } h;
    };
    __shared__ SharedU u;
    __shared__ float wred[4];

    const int tid = threadIdx.x;
    const int x0 = blockIdx.x * TW - 5;
    const int y0 = blockIdx.y * TH - 5;
    const bool interior =
        blockIdx.x > 0 && blockIdx.x < gridDim.x - 1 &&
        blockIdx.y > 0 && blockIdx.y < gridDim.y - 1;

    const int r0 = tid / IN_W;
    const int c0 = tid - r0 * IN_W;
    const int goff0 = (y0 + r0) * IMG_W + (x0 + c0);
    const int loff0 = r0 * S12_STR + c0;

    const int r2 = tid >> 2;            // phase-2 row
    const int cb = (tid & 3) * 8;       // phase-2 col base
    const int c3 = tid & 31;            // phase-3 col
    const int rb = (tid >> 5) * 4;      // phase-3 row base

    float lsum = 0.f;

#pragma unroll 1
    for (int ch = 0; ch < CH_PER_BLOCK; ++ch) {
        const size_t base =
            (size_t)(blockIdx.z * CH_PER_BLOCK + ch) * (IMG_W * IMG_H);
        const float* p1 = img1 + base;
        const float* p2 = img2 + base;

        // ---- Phase 1: global -> LDS, incremental addressing ----
        {
            int r = r0, c = c0, goff = goff0, loff = loff0;
            if (interior) {
#pragma unroll
                for (int i = 0; i < 7; ++i) {
                    if (i < 6 || tid < IN_H * IN_W - 6 * 256) {   // 228
                        v2f t; t.x = p1[goff]; t.y = p2[goff];
                        u.s12[loff] = t;
                    }
                    const bool wrap = (c + 4) >= IN_W;
                    c    += wrap ? 4 - IN_W : 4;
                    goff += wrap ? 7 * IMG_W - (IN_W - 4) : 6 * IMG_W + 4;
                    loff += wrap ? 7 * S12_STR - (IN_W - 4) : 6 * S12_STR + 4;
                    r    += wrap ? 7 : 6;
                }
            } else {
#pragma unroll
                for (int i = 0; i < 7; ++i) {
                    if (i < 6 || tid < IN_H * IN_W - 6 * 256) {
                        const int gy = y0 + r, gx = x0 + c;
                        v2f t; t.x = 0.f; t.y = 0.f;
                        if (gy >= 0 && gy < IMG_H && gx >= 0 && gx < IMG_W) {
                            t.x = p1[goff]; t.y = p2[goff];
                        }
                        u.s12[loff] = t;
                    }
                    const bool wrap = (c + 4) >= IN_W;
                    c    += wrap ? 4 - IN_W : 4;
                    goff += wrap ? 7 * IMG_W - (IN_W - 4) : 6 * IMG_W + 4;
                    loff += wrap ? 7 * S12_STR - (IN_W - 4) : 6 * S12_STR + 4;
                    r    += wrap ? 7 : 6;
                }
            }
        }
        __syncthreads();

        // ---- Phase 2: horizontal 11-tap, scatter form, packed xy ----
        v2f mu8[8], sq8[8], xy2[4];
        if (tid < 168) {
#pragma unroll
            for (int j = 0; j < 8; ++j) { mu8[j] = bcast(0.f); sq8[j] = bcast(0.f); }
#pragma unroll
            for (int p = 0; p < 4; ++p) xy2[p] = bcast(0.f);
            const v4f* srow = (const v4f*)&u.s12[r2 * S12_STR + cb];
#pragma unroll
            for (int m = 0; m < 9; ++m) {
                const v4f q = srow[m];
#pragma unroll
                for (int half = 0; half < 2; ++half) {
                    const int k = 2 * m + half;
                    v2f v;
                    v.x = half ? q.z : q.x;
                    v.y = half ? q.w : q.y;
                    const v2f a2 = pkmul(v, v);
                    v2f xyd;                       // {x*y, x*y}
                    xyd.x = v.x * v.y;
                    xyd.y = xyd.x;
#pragma unroll
                    for (int j = 0; j < 8; ++j) {
                        const int t = k - j;
                        if (t >= 0 && t < 11) {
                            const v2f w2 = bcast(GW[t]);
                            pkfma(mu8[j], w2, v);
                            pkfma(sq8[j], w2, a2);
                        }
                    }
#pragma unroll
                    for (int p = 0; p < 4; ++p) {
                        const int t = k - 2 * p;
                        if (t >= 0 && t <= 11) {
                            v2f wp; wp.x = GWZ(t); wp.y = GWZ(t - 1);
                            pkfma(xy2[p], wp, xyd);
                        }
                    }
                }
            }
        }
        __syncthreads();            // all reads of s12 done; safe to overwrite
        if (tid < 168) {
#pragma unroll
            for (int j = 0; j < 8; ++j) {
                const int idx = hidx(r2, cb + j);
                v4f q;
                q.x = mu8[j].x; q.y = mu8[j].y;
                q.z = sq8[j].x; q.w = sq8[j].y;
                u.h.h4 [idx] = q;
                u.h.hab[idx] = (j & 1) ? xy2[j >> 1].y : xy2[j >> 1].x;
            }
        }
        __syncthreads();

        // ---- Phase 3: vertical 11-tap + SSIM, scatter form, 4 rows/thread ----
        v2f mu4[4], sg4[4];
        float xy4[4];
#pragma unroll
        for (int j = 0; j < 4; ++j) {
            mu4[j] = bcast(0.f); sg4[j] = bcast(0.f); xy4[j] = 0.f;
        }
#pragma unroll
        for (int k = 0; k < 14; ++k) {
            const int idx = hidx(rb + k, c3);
            const v4f q = u.h.h4[idx];
            const float hx = u.h.hab[idx];
            v2f hm; hm.x = q.x; hm.y = q.y;
            v2f hs; hs.x = q.z; hs.y = q.w;
#pragma unroll
            for (int j = 0; j < 4; ++j) {
                const int t = k - j;
                if (t >= 0 && t < 11) {
                    const v2f w2 = bcast(GW[t]);
                    pkfma(mu4[j], w2, hm);
                    pkfma(sg4[j], w2, hs);
                    xy4[j] = fmaf(GW[t], hx, xy4[j]);
                }
            }
        }
#pragma unroll
        for (int j = 0; j < 4; ++j) {
            const v2f musq = pkmul(mu4[j], mu4[j]);      // {mu1^2, mu2^2}
            const float mu12 = mu4[j].x * mu4[j].y;
            const float s1 = sg4[j].x - musq.x, s2 = sg4[j].y - musq.y;
            const float s12v = xy4[j] - mu12;
            const float num = (2.f * mu12 + C1c) * (2.f * s12v + C2c);
            const float den = (musq.x + musq.y + C1c) * (s1 + s2 + C2c);
            lsum += __fdividef(num, den);
        }
        __syncthreads();    // phase-3 h reads done before next tile's s12 write
    }

    // ---- Phase 4: block reduce (once) -> double atomic into 256 ws slots ----
#pragma unroll
    for (int off = 32; off > 0; off >>= 1)
        lsum += __shfl_down(lsum, off, 64);
    if ((tid & 63) == 0) wred[tid >> 6] = lsum;
    __syncthreads();
    if (tid == 0) {
        const int bid = (blockIdx.z * gridDim.y + blockIdx.y) * gridDim.x + blockIdx.x;
        unsafeAtomicAdd(&acc[bid & 255],
                        (double)(wred[0] + wred[1] + wred[2] + wred[3]));
    }
}

__global__ __launch_bounds__(256) void ssim_final_kernel(
        const double* __restrict__ acc, float* __restrict__ out, double inv_total)
{
    const int tid = threadIdx.x;
    double a = acc[tid];
#pragma unroll
    for (int off = 32; off > 0; off >>= 1)
        a += __shfl_down(a, off, 64);
    __shared__ double ws[4];
    if ((tid & 63) == 0) ws[tid >> 6] = a;
    __syncthreads();
    if (tid == 0)
        out[0] = (float)((ws[0] + ws[1] + ws[2] + ws[3]) * inv_total);
}

extern "C" void kernel_launch(void* const* d_in, const int* in_sizes, int n_in,
                              void* d_out, int out_size, void* d_ws, size_t ws_size,
                              hipStream_t stream)
{
    const float* img1 = (const float*)d_in[0];
    const float* img2 = (const float*)d_in[1];
    double* acc = (double*)d_ws;

    hipMemsetAsync(d_ws, 0, 256 * sizeof(double), stream);

    const int nch = in_sizes[0] / (IMG_W * IMG_H);      // 16*3 = 48
    dim3 grid(IMG_W / TW, IMG_H / TH, nch / CH_PER_BLOCK);  // 16 x 16 x 12
    ssim_tile_kernel<<<grid, 256, 0, stream>>>(img1, img2, acc);

    const double inv_total = 1.0 / (double)in_sizes[0];
    ssim_final_kernel<<<1, 256, 0, stream>>>(acc, (float*)d_out, inv_total);
}

// Round 9
// 162.945 us; speedup vs baseline: 2.5297x; 1.6685x over previous
//
#include <hip/hip_runtime.h>

namespace {
constexpr int IMG_W = 512, IMG_H = 512;
constexpr int TW = 32, TH = 32;
constexpr int IN_W = TW + 10, IN_H = TH + 10;   // 42 (pixel window actually used)
constexpr int S12_STR = 46;  // v2f units/row (uses 44: window starts at x0-1), even -> b128 rows aligned
constexpr float C1c = 0.01f * 0.01f;
constexpr float C2c = 0.03f * 0.03f;

constexpr float GW[11] = {
    1.0283799e-03f, 7.5987582e-03f, 3.6000773e-02f, 1.0936069e-01f,
    2.1300554e-01f, 2.6601172e-01f, 2.1300554e-01f, 1.0936069e-01f,
    3.6000773e-02f, 7.5987582e-03f, 1.0283799e-03f
};
constexpr float GWZ(int t) { return (t >= 0 && t < 11) ? GW[t] : 0.f; }

using v2f = __attribute__((ext_vector_type(2))) float;
using v4f = __attribute__((ext_vector_type(4))) float;

// In-place packed FMA, weight in SGPR pair: acc += w * a.
__device__ __forceinline__ void pkfma(v2f& acc, v2f w, v2f a) {
    asm("v_pk_fma_f32 %0, %1, %2, %0" : "+v"(acc) : "s"(w), "v"(a));
}
__device__ __forceinline__ v2f pkmul(v2f a, v2f b) {
    v2f d;
    asm("v_pk_mul_f32 %0, %1, %2" : "=v"(d) : "v"(a), "v"(b));
    return d;
}
__device__ __forceinline__ v2f bcast(float w) { v2f r; r.x = w; r.y = w; return r; }

// h-planes: stride 32 + rotate swizzle (col+row)&31
__device__ __forceinline__ int hidx(int row, int col) {
    return row * 32 + ((col + row) & 31);
}
}

__global__ __launch_bounds__(256, 6) void ssim_tile_kernel(
        const float* __restrict__ img1, const float* __restrict__ img2,
        double* __restrict__ acc)
{
    union SharedU {
        v2f s12[IN_H * S12_STR];                // 15456 B; col c = pixel x0e+c
        struct {
            v4f   h4 [IN_H * 32];               // 21504 B (mu1,mu2,Exx,Eyy) swizzled
            float hab[IN_H * 32];               //  5376 B (Exy) swizzled
        } h;
    };
    __shared__ SharedU u;
    __shared__ float wred[4];

    const int tid = threadIdx.x;
    const size_t base = (size_t)blockIdx.z * (IMG_W * IMG_H);
    const float* p1 = img1 + base;
    const float* p2 = img2 + base;
    const int x0e = blockIdx.x * TW - 6;    // even; window cols 0..43 = pixels x0e..x0e+43
    const int y0  = blockIdx.y * TH - 5;

    // ---- Phase 1: global -> LDS, 2 pixels/thread, b128 interleaved stores ----
    // 42 rows x 22 f2-units = 924 units; 4 iterations of 256.
    {
        v4f* s12v4 = (v4f*)u.s12;               // row stride 23 v4f units
        int r   = tid / 22;
        int cf2 = tid - r * 22;
        int goff = (y0 + r) * IMG_W + x0e + 2 * cf2;
        int soff = r * 23 + cf2;
        const bool interior =
            blockIdx.x > 0 && blockIdx.x < gridDim.x - 1 &&
            blockIdx.y > 0 && blockIdx.y < gridDim.y - 1;
        if (interior) {
#pragma unroll
            for (int i = 0; i < 4; ++i) {
                if (i < 3 || tid < 924 - 3 * 256) {     // 156
                    const float2 a = *(const float2*)&p1[goff];
                    const float2 b = *(const float2*)&p2[goff];
                    v4f q; q.x = a.x; q.y = b.x; q.z = a.y; q.w = b.y;
                    s12v4[soff] = q;
                }
                const bool wrap = cf2 + 14 >= 22;
                cf2  += wrap ? -8 : 14;
                r    += wrap ? 12 : 11;
                goff += wrap ? 12 * IMG_W - 16 : 11 * IMG_W + 28;
                soff += wrap ? 12 * 23 - 8     : 11 * 23 + 14;
            }
        } else {
#pragma unroll
            for (int i = 0; i < 4; ++i) {
                if (i < 3 || tid < 924 - 3 * 256) {
                    const int gy = y0 + r;
                    const int gx = x0e + 2 * cf2;
                    float a0 = 0.f, a1 = 0.f, b0 = 0.f, b1 = 0.f;
                    if (gy >= 0 && gy < IMG_H) {
                        if (gx >= 0 && gx < IMG_W)         { a0 = p1[goff];     b0 = p2[goff]; }
                        if (gx + 1 >= 0 && gx + 1 < IMG_W) { a1 = p1[goff + 1]; b1 = p2[goff + 1]; }
                    }
                    v4f q; q.x = a0; q.y = b0; q.z = a1; q.w = b1;
                    s12v4[soff] = q;
                }
                const bool wrap = cf2 + 14 >= 22;
                cf2  += wrap ? -8 : 14;
                r    += wrap ? 12 : 11;
                goff += wrap ? 12 * IMG_W - 16 : 11 * IMG_W + 28;
                soff += wrap ? 12 * 23 - 8     : 11 * 23 + 14;
            }
        }
    }
    __syncthreads();

    // ---- Phase 2: horizontal 11-tap, scatter form, packed xy ----
    // 42 rows x 4 col-groups x 8 outputs = 168 active threads.
    // Window col k (v2f) = pixel x0e + 8g + k; output j taps t = k - j - 1.
    const int r2 = tid >> 2;
    const int g2 = tid & 3;
    const int cb = g2 * 8;
    v2f mu8[8], sq8[8], xy2[4];
    if (tid < 168) {
#pragma unroll
        for (int j = 0; j < 8; ++j) { mu8[j] = bcast(0.f); sq8[j] = bcast(0.f); }
#pragma unroll
        for (int p = 0; p < 4; ++p) xy2[p] = bcast(0.f);
        const v4f* srow = (const v4f*)u.s12 + (r2 * 23 + g2 * 4);
#pragma unroll
        for (int m = 0; m < 10; ++m) {
            const v4f q = srow[m];
#pragma unroll
            for (int half = 0; half < 2; ++half) {
                const int k = 2 * m + half;
                v2f v;
                v.x = half ? q.z : q.x;
                v.y = half ? q.w : q.y;
                const v2f a2 = pkmul(v, v);
                v2f xyd;                       // {x*y, x*y}
                xyd.x = v.x * v.y;
                xyd.y = xyd.x;
#pragma unroll
                for (int j = 0; j < 8; ++j) {
                    const int t = k - j - 1;
                    if (t >= 0 && t < 11) {
                        const v2f w2 = bcast(GW[t]);
                        pkfma(mu8[j], w2, v);
                        pkfma(sq8[j], w2, a2);
                    }
                }
#pragma unroll
                for (int p = 0; p < 4; ++p) {
                    const int t = k - 2 * p - 1;
                    if (t >= 0 && t <= 11) {
                        v2f wp; wp.x = GWZ(t); wp.y = GWZ(t - 1);
                        pkfma(xy2[p], wp, xyd);
                    }
                }
            }
        }
    }
    __syncthreads();            // all reads of s12 done; safe to overwrite
    if (tid < 168) {
#pragma unroll
        for (int j = 0; j < 8; ++j) {
            const int idx = hidx(r2, cb + j);
            v4f q;
            q.x = mu8[j].x; q.y = mu8[j].y;
            q.z = sq8[j].x; q.w = sq8[j].y;
            u.h.h4 [idx] = q;
            u.h.hab[idx] = (j & 1) ? xy2[j >> 1].y : xy2[j >> 1].x;
        }
    }
    __syncthreads();

    // ---- Phase 3: vertical 11-tap + SSIM, scatter form, 4 rows/thread ----
    const int c3 = tid & 31;
    const int rb = (tid >> 5) * 4;
    v2f mu4[4], sg4[4];
    float xy4[4];
#pragma unroll
    for (int j = 0; j < 4; ++j) {
        mu4[j] = bcast(0.f); sg4[j] = bcast(0.f); xy4[j] = 0.f;
    }
#pragma unroll
    for (int k = 0; k < 14; ++k) {
        const int idx = hidx(rb + k, c3);
        const v4f q = u.h.h4[idx];
        const float hx = u.h.hab[idx];
        v2f hm; hm.x = q.x; hm.y = q.y;
        v2f hs; hs.x = q.z; hs.y = q.w;
#pragma unroll
        for (int j = 0; j < 4; ++j) {
            const int t = k - j;
            if (t >= 0 && t < 11) {
                const v2f w2 = bcast(GW[t]);
                pkfma(mu4[j], w2, hm);
                pkfma(sg4[j], w2, hs);
                xy4[j] = fmaf(GW[t], hx, xy4[j]);
            }
        }
    }
    float lsum = 0.f;
#pragma unroll
    for (int j = 0; j < 4; ++j) {
        const v2f musq = pkmul(mu4[j], mu4[j]);      // {mu1^2, mu2^2}
        const float mu12 = mu4[j].x * mu4[j].y;
        const float s1 = sg4[j].x - musq.x, s2 = sg4[j].y - musq.y;
        const float s12v = xy4[j] - mu12;
        const float num = (2.f * mu12 + C1c) * (2.f * s12v + C2c);
        const float den = (musq.x + musq.y + C1c) * (s1 + s2 + C2c);
        lsum += __fdividef(num, den);
    }

    // ---- Phase 4: block reduce -> double atomic into 256 ws slots ----
#pragma unroll
    for (int off = 32; off > 0; off >>= 1)
        lsum += __shfl_down(lsum, off, 64);
    if ((tid & 63) == 0) wred[tid >> 6] = lsum;
    __syncthreads();
    if (tid == 0) {
        const int bid = (blockIdx.z * gridDim.y + blockIdx.y) * gridDim.x + blockIdx.x;
        unsafeAtomicAdd(&acc[bid & 255],
                        (double)(wred[0] + wred[1] + wred[2] + wred[3]));
    }
}

__global__ __launch_bounds__(256) void ssim_final_kernel(
        const double* __restrict__ acc, float* __restrict__ out, double inv_total)
{
    const int tid = threadIdx.x;
    double a = acc[tid];
#pragma unroll
    for (int off = 32; off > 0; off >>= 1)
        a += __shfl_down(a, off, 64);
    __shared__ double ws[4];
    if ((tid & 63) == 0) ws[tid >> 6] = a;
    __syncthreads();
    if (tid == 0)
        out[0] = (float)((ws[0] + ws[1] + ws[2] + ws[3]) * inv_total);
}

extern "C" void kernel_launch(void* const* d_in, const int* in_sizes, int n_in,
                              void* d_out, int out_size, void* d_ws, size_t ws_size,
                              hipStream_t stream)
{
    const float* img1 = (const float*)d_in[0];
    const float* img2 = (const float*)d_in[1];
    double* acc = (double*)d_ws;

    hipMemsetAsync(d_ws, 0, 256 * sizeof(double), stream);

    const int nch = in_sizes[0] / (IMG_W * IMG_H);      // 16*3 = 48
    dim3 grid(IMG_W / TW, IMG_H / TH, nch);             // 16 x 16 x 48
    ssim_tile_kernel<<<grid, 256, 0, stream>>>(img1, img2, acc);

    const double inv_total = 1.0 / (double)in_sizes[0];
    ssim_final_kernel<<<1, 256, 0, stream>>>(acc, (float*)d_out, inv_total);
}

// Round 10
// 153.013 us; speedup vs baseline: 2.6939x; 1.0649x over previous
//
#include <hip/hip_runtime.h>

namespace {
constexpr int IMG_W = 512, IMG_H = 512;
constexpr int TW = 32, TH = 32;
constexpr int IN_W = TW + 10, IN_H = TH + 10;   // 42 (pixel window actually used)
constexpr int S12_STR = 46;  // v2f units/row (uses 44: window starts at x0-1)
constexpr float C1c = 0.01f * 0.01f;
constexpr float C2c = 0.03f * 0.03f;

constexpr float GW[11] = {
    1.0283799e-03f, 7.5987582e-03f, 3.6000773e-02f, 1.0936069e-01f,
    2.1300554e-01f, 2.6601172e-01f, 2.1300554e-01f, 1.0936069e-01f,
    3.6000773e-02f, 7.5987582e-03f, 1.0283799e-03f
};

using v2f = __attribute__((ext_vector_type(2))) float;
using v4f = __attribute__((ext_vector_type(4))) float;

// In-place packed FMA, weight in SGPR pair: acc += w * a.
__device__ __forceinline__ void pkfma(v2f& acc, v2f w, v2f a) {
    asm("v_pk_fma_f32 %0, %1, %2, %0" : "+v"(acc) : "s"(w), "v"(a));
}
__device__ __forceinline__ v2f pkmul(v2f a, v2f b) {
    v2f d;
    asm("v_pk_mul_f32 %0, %1, %2" : "=v"(d) : "v"(a), "v"(b));
    return d;
}
__device__ __forceinline__ v2f bcast(float w) { v2f r; r.x = w; r.y = w; return r; }

// h-plane: stride 32 + rotate swizzle (col+row)&31
__device__ __forceinline__ int hidx(int row, int col) {
    return row * 32 + ((col + row) & 31);
}
}

// SSIM only ever consumes Exx+Eyy (never separately): phase 2 emits
// (mu1, mu2, ss=conv(x^2+y^2), xy=conv(x*y)) -> one v4f plane, 21.5 KB LDS
// union -> 7 blocks/CU. (256,6): allocator cap 85, known spill-free.
__global__ __launch_bounds__(256, 6) void ssim_tile_kernel(
        const float* __restrict__ img1, const float* __restrict__ img2,
        double* __restrict__ acc)
{
    union SharedU {
        v2f s12[IN_H * S12_STR];                // 15456 B; col c = pixel x0e+c
        v4f h4 [IN_H * 32];                     // 21504 B (mu1,mu2,ss,xy) swizzled
    };
    __shared__ SharedU u;
    __shared__ float wred[4];

    const int tid = threadIdx.x;
    const size_t base = (size_t)blockIdx.z * (IMG_W * IMG_H);
    const float* p1 = img1 + base;
    const float* p2 = img2 + base;
    const int x0e = blockIdx.x * TW - 6;    // even; window cols 0..43 = pixels x0e..x0e+43
    const int y0  = blockIdx.y * TH - 5;

    // ---- Phase 1: global -> LDS, 2 pixels/thread, b128 interleaved stores ----
    // 42 rows x 22 f2-units = 924 units; 4 iterations of 256.
    {
        v4f* s12v4 = (v4f*)u.s12;               // row stride 23 v4f units
        int r   = tid / 22;
        int cf2 = tid - r * 22;
        int goff = (y0 + r) * IMG_W + x0e + 2 * cf2;
        int soff = r * 23 + cf2;
        const bool interior =
            blockIdx.x > 0 && blockIdx.x < gridDim.x - 1 &&
            blockIdx.y > 0 && blockIdx.y < gridDim.y - 1;
        if (interior) {
#pragma unroll
            for (int i = 0; i < 4; ++i) {
                if (i < 3 || tid < 924 - 3 * 256) {     // 156
                    const float2 a = *(const float2*)&p1[goff];
                    const float2 b = *(const float2*)&p2[goff];
                    v4f q; q.x = a.x; q.y = b.x; q.z = a.y; q.w = b.y;
                    s12v4[soff] = q;
                }
                const bool wrap = cf2 + 14 >= 22;
                cf2  += wrap ? -8 : 14;
                r    += wrap ? 12 : 11;
                goff += wrap ? 12 * IMG_W - 16 : 11 * IMG_W + 28;
                soff += wrap ? 12 * 23 - 8     : 11 * 23 + 14;
            }
        } else {
#pragma unroll
            for (int i = 0; i < 4; ++i) {
                if (i < 3 || tid < 924 - 3 * 256) {
                    const int gy = y0 + r;
                    const int gx = x0e + 2 * cf2;
                    float a0 = 0.f, a1 = 0.f, b0 = 0.f, b1 = 0.f;
                    if (gy >= 0 && gy < IMG_H) {
                        if (gx >= 0 && gx < IMG_W)         { a0 = p1[goff];     b0 = p2[goff]; }
                        if (gx + 1 >= 0 && gx + 1 < IMG_W) { a1 = p1[goff + 1]; b1 = p2[goff + 1]; }
                    }
                    v4f q; q.x = a0; q.y = b0; q.z = a1; q.w = b1;
                    s12v4[soff] = q;
                }
                const bool wrap = cf2 + 14 >= 22;
                cf2  += wrap ? -8 : 14;
                r    += wrap ? 12 : 11;
                goff += wrap ? 12 * IMG_W - 16 : 11 * IMG_W + 28;
                soff += wrap ? 12 * 23 - 8     : 11 * 23 + 14;
            }
        }
    }
    __syncthreads();

    // ---- Phase 2: horizontal 11-tap, scatter form ----
    // 42 rows x 4 col-groups x 8 outputs = 168 active threads.
    // Window col k (v2f) = pixel x0e + 8g + k; output j taps t = k - j - 1.
    const int r2 = tid >> 2;
    const int g2 = tid & 3;
    const int cb = g2 * 8;
    v2f mu8[8], sx8[8];     // mu8 = {mu1,mu2}; sx8 = {ss, xy}
    if (tid < 168) {
#pragma unroll
        for (int j = 0; j < 8; ++j) { mu8[j] = bcast(0.f); sx8[j] = bcast(0.f); }
        const v4f* srow = (const v4f*)u.s12 + (r2 * 23 + g2 * 4);
#pragma unroll
        for (int m = 0; m < 10; ++m) {
            const v4f q = srow[m];
#pragma unroll
            for (int half = 0; half < 2; ++half) {
                const int k = 2 * m + half;
                v2f v;
                v.x = half ? q.z : q.x;
                v.y = half ? q.w : q.y;
                const v2f a2 = pkmul(v, v);
                v2f sx;                         // {x^2+y^2, x*y}
                sx.x = a2.x + a2.y;
                sx.y = v.x * v.y;
#pragma unroll
                for (int j = 0; j < 8; ++j) {
                    const int t = k - j - 1;
                    if (t >= 0 && t < 11) {
                        const v2f w2 = bcast(GW[t]);
                        pkfma(mu8[j], w2, v);
                        pkfma(sx8[j], w2, sx);
                    }
                }
            }
        }
    }
    __syncthreads();            // all reads of s12 done; safe to overwrite
    if (tid < 168) {
#pragma unroll
        for (int j = 0; j < 8; ++j) {
            v4f q;
            q.x = mu8[j].x; q.y = mu8[j].y;
            q.z = sx8[j].x; q.w = sx8[j].y;
            u.h4[hidx(r2, cb + j)] = q;
        }
    }
    __syncthreads();

    // ---- Phase 3: vertical 11-tap + SSIM, scatter form, 4 rows/thread ----
    const int c3 = tid & 31;
    const int rb = (tid >> 5) * 4;
    v2f mu4[4], sx4[4];
#pragma unroll
    for (int j = 0; j < 4; ++j) { mu4[j] = bcast(0.f); sx4[j] = bcast(0.f); }
#pragma unroll
    for (int k = 0; k < 14; ++k) {
        const v4f q = u.h4[hidx(rb + k, c3)];
        v2f hm; hm.x = q.x; hm.y = q.y;
        v2f hx; hx.x = q.z; hx.y = q.w;
#pragma unroll
        for (int j = 0; j < 4; ++j) {
            const int t = k - j;
            if (t >= 0 && t < 11) {
                const v2f w2 = bcast(GW[t]);
                pkfma(mu4[j], w2, hm);
                pkfma(sx4[j], w2, hx);
            }
        }
    }
    float lsum = 0.f;
#pragma unroll
    for (int j = 0; j < 4; ++j) {
        const v2f musq = pkmul(mu4[j], mu4[j]);      // {mu1^2, mu2^2}
        const float mu12 = mu4[j].x * mu4[j].y;
        const float sden = musq.x + musq.y;           // mu1^2 + mu2^2
        const float s12v = sx4[j].y - mu12;           // sigma12
        const float ssum = sx4[j].x - sden;           // sigma1^2 + sigma2^2
        const float num = (2.f * mu12 + C1c) * (2.f * s12v + C2c);
        const float den = (sden + C1c) * (ssum + C2c);
        lsum += __fdividef(num, den);
    }

    // ---- Phase 4: block reduce -> double atomic into 256 ws slots ----
#pragma unroll
    for (int off = 32; off > 0; off >>= 1)
        lsum += __shfl_down(lsum, off, 64);
    if ((tid & 63) == 0) wred[tid >> 6] = lsum;
    __syncthreads();
    if (tid == 0) {
        const int bid = (blockIdx.z * gridDim.y + blockIdx.y) * gridDim.x + blockIdx.x;
        unsafeAtomicAdd(&acc[bid & 255],
                        (double)(wred[0] + wred[1] + wred[2] + wred[3]));
    }
}

__global__ __launch_bounds__(256) void ssim_final_kernel(
        const double* __restrict__ acc, float* __restrict__ out, double inv_total)
{
    const int tid = threadIdx.x;
    double a = acc[tid];
#pragma unroll
    for (int off = 32; off > 0; off >>= 1)
        a += __shfl_down(a, off, 64);
    __shared__ double ws[4];
    if ((tid & 63) == 0) ws[tid >> 6] = a;
    __syncthreads();
    if (tid == 0)
        out[0] = (float)((ws[0] + ws[1] + ws[2] + ws[3]) * inv_total);
}

extern "C" void kernel_launch(void* const* d_in, const int* in_sizes, int n_in,
                              void* d_out, int out_size, void* d_ws, size_t ws_size,
                              hipStream_t stream)
{
    const float* img1 = (const float*)d_in[0];
    const float* img2 = (const float*)d_in[1];
    double* acc = (double*)d_ws;

    hipMemsetAsync(d_ws, 0, 256 * sizeof(double), stream);

    const int nch = in_sizes[0] / (IMG_W * IMG_H);      // 16*3 = 48
    dim3 grid(IMG_W / TW, IMG_H / TH, nch);             // 16 x 16 x 48
    ssim_tile_kernel<<<grid, 256, 0, stream>>>(img1, img2, acc);

    const double inv_total = 1.0 / (double)in_sizes[0];
    ssim_final_kernel<<<1, 256, 0, stream>>>(acc, (float*)d_out, inv_total);
}